// Round 5
// baseline (666.028 us; speedup 1.0000x reference)
//
#include <hip/hip_runtime.h>
#include <math.h>

#define LL 25600          // H*W
#define NTOTF 51200.f     // B*L (batch-norm N)

using f16   = _Float16;
using f16x8 = __attribute__((ext_vector_type(8))) _Float16;
using f16x4 = __attribute__((ext_vector_type(4))) _Float16;
using f32x4 = __attribute__((ext_vector_type(4))) float;

__device__ __forceinline__ float gelu_f(float v) {
    return 0.5f * v * (1.f + erff(v * 0.70710678118654752440f));
}

// ---------------------------------------------------------------------------
// f16 MFMA GEMM:  Y[b, o, p] = bias[o] + sum_c W[o,c] * X[b, c, p]
//   X: [B, K, LL] (fp32 if IN32 else f16); W: fp32 [M,K] row-major
//   (TWOW: rows 0-127 from WA, 128-255 from WB); Y: f16 [B, M, LL].
//   LDG: apply BN(lstat)+GELU to X elements while staging to LDS.
//   STATS: accumulate per-o sum/sumsq of Y (pre-f16-rounding) into ostat[2M].
// W lives in REGISTERS (per-wave A-fragments, loaded once from global; the
// 16x16x32 A-frag is 8 contiguous row elements per lane -> two float4 loads).
// X chunk (64 positions) staged in LDS, XOR-swizzled; double-buffered iff LOOP.
// LOOP=false requires grid == nchunk (one chunk per block, single buffer).
// Block: 256 thr (4 waves), wave owns M/4 rows.
// ---------------------------------------------------------------------------
template <int M, int K, bool LOOP, bool IN32, bool LDG, bool TWOW, bool BIAS, bool STATS>
__global__ __launch_bounds__(256) void gemm_kernel(
    const void* __restrict__ Xin,
    const float* __restrict__ WA, const float* __restrict__ WB,
    const float* __restrict__ biasA, const float* __restrict__ biasB,
    const float* __restrict__ lstat,     // [2K] sum|sq for load-side BN
    f16* __restrict__ Y,
    float* __restrict__ ostat,           // [2M] sum|sq
    int nchunk)
{
    constexpr int MR   = M / 64;    // 16-row frags per wave per k-step
    constexpr int KS   = K / 32;    // k-steps
    constexpr int CPT  = K / 4;     // channels staged per thread
    constexpr int NBUF = LOOP ? 2 : 1;
    static_assert(CPT % 8 == 0, "");

    __shared__ f16 Xs[NBUF][64 * K];
    __shared__ float lmrs[LDG ? 2 * K : 2];

    const int tid  = threadIdx.x;
    const int lane = tid & 63;
    const int wv   = tid >> 6;
    const int lm16 = lane & 15, lg = lane >> 4;
    const int row0 = wv * (M / 4);
    const int i    = lane;          // position within chunk
    const int g0   = wv * CPT;      // first channel staged by this thread

    // ---- A-fragments (weights) -> registers, fp32 -> f16 ----
    f16x8 afr[KS][MR];
#pragma unroll
    for (int k = 0; k < KS; ++k) {
        const int col = k * 32 + lg * 8;
#pragma unroll
        for (int mr = 0; mr < MR; ++mr) {
            const int row = row0 + mr * 16 + lm16;
            const float* wp = (TWOW && row >= 128)
                                  ? WB + (size_t)(row - 128) * K + col
                                  : WA + (size_t)row * K + col;
            const float4 wa = *reinterpret_cast<const float4*>(wp);
            const float4 wb2 = *reinterpret_cast<const float4*>(wp + 4);
            f16x8 v;
            v[0] = (f16)wa.x; v[1] = (f16)wa.y; v[2] = (f16)wa.z; v[3] = (f16)wa.w;
            v[4] = (f16)wb2.x; v[5] = (f16)wb2.y; v[6] = (f16)wb2.z; v[7] = (f16)wb2.w;
            afr[k][mr] = v;
        }
    }
    if (LDG) {
        for (int c = tid; c < K; c += 256) {
            const float m  = lstat[c] * (1.f / NTOTF);
            const float va = lstat[K + c] * (1.f / NTOTF) - m * m;
            lmrs[c] = m; lmrs[K + c] = rsqrtf(va + 1e-5f);
        }
    }

    // ---- bias (hoisted) + stats regs ----
    float bv[MR][4];
#pragma unroll
    for (int mr = 0; mr < MR; ++mr)
#pragma unroll
        for (int r = 0; r < 4; ++r) {
            if (BIAS) {
                const int o = row0 + mr * 16 + lg * 4 + r;
                bv[mr][r] = (TWOW && o >= 128) ? biasB[o - 128] : biasA[o];
            } else bv[mr][r] = 0.f;
        }
    float st1[MR][4], st2[MR][4];
#pragma unroll
    for (int mr = 0; mr < MR; ++mr)
#pragma unroll
        for (int r = 0; r < 4; ++r) { st1[mr][r] = 0.f; st2[mr][r] = 0.f; }

    float xr[CPT];
    auto load_regs = [&](int t) {
        const int bb = t / 400, pp0 = (t - bb * 400) * 64;
#pragma unroll
        for (int j = 0; j < CPT; ++j) {
            const size_t off = (size_t)(bb * K + g0 + j) * LL + pp0 + i;
            xr[j] = IN32 ? reinterpret_cast<const float*>(Xin)[off]
                         : (float)reinterpret_cast<const f16*>(Xin)[off];
        }
    };
    auto store_lds = [&](int buf) {
#pragma unroll
        for (int j = 0; j < CPT; j += 8) {
            f16x8 v8;
#pragma unroll
            for (int jj = 0; jj < 8; ++jj) {
                float v = xr[j + jj];
                if (LDG) {
                    const int c = g0 + j + jj;
                    v = gelu_f((v - lmrs[c]) * lmrs[K + c]);
                }
                v8[jj] = (f16)v;
            }
            const int c0 = g0 + j;
            *reinterpret_cast<f16x8*>(
                &Xs[buf][(size_t)i * K + (c0 ^ ((i & 7) << 3))]) = v8;
        }
    };

    __syncthreads();                       // lmrs visible
    int t = blockIdx.x;
    int cur = 0;
    load_regs(t);
    store_lds(0);
    __syncthreads();

    while (true) {
        const int tn = t + gridDim.x;
        const bool nxt = LOOP && (tn < nchunk);
        if (nxt) load_regs(tn);            // global loads in flight

        const int bb = t / 400, pp0 = (t - bb * 400) * 64;
        f32x4 acc[MR][4];
#pragma unroll
        for (int mr = 0; mr < MR; ++mr)
#pragma unroll
            for (int nr = 0; nr < 4; ++nr)
                acc[mr][nr] = (f32x4){0.f, 0.f, 0.f, 0.f};

#pragma unroll
        for (int k = 0; k < KS; ++k) {
            const int kc = k * 32 + lg * 8;
            f16x8 bfr[4];
#pragma unroll
            for (int nr = 0; nr < 4; ++nr) {
                const int pos = nr * 16 + lm16;
                bfr[nr] = *reinterpret_cast<const f16x8*>(
                    &Xs[cur][(size_t)pos * K + (kc ^ ((pos & 7) << 3))]);
            }
#pragma unroll
            for (int mr = 0; mr < MR; ++mr)
#pragma unroll
                for (int nr = 0; nr < 4; ++nr)
                    acc[mr][nr] = __builtin_amdgcn_mfma_f32_16x16x32_f16(
                        afr[k][mr], bfr[nr], acc[mr][nr], 0, 0, 0);
        }

        // epilogue: bias, store f16, stats
#pragma unroll
        for (int mr = 0; mr < MR; ++mr)
#pragma unroll
            for (int r = 0; r < 4; ++r) {
                const int o = row0 + mr * 16 + lg * 4 + r;
                f16* yb = Y + (size_t)(bb * M + o) * LL + pp0 + lm16;
#pragma unroll
                for (int nr = 0; nr < 4; ++nr) {
                    const float v = acc[mr][nr][r] + bv[mr][r];
                    yb[nr * 16] = (f16)v;
                    if (STATS) { st1[mr][r] += v; st2[mr][r] += v * v; }
                }
            }

        if (!nxt) break;
        store_lds(cur ^ 1);
        __syncthreads();
        cur ^= 1; t = tn;
    }

    if (STATS) {
#pragma unroll
        for (int mr = 0; mr < MR; ++mr)
#pragma unroll
            for (int r = 0; r < 4; ++r) {
                float s1 = st1[mr][r], s2 = st2[mr][r];
#pragma unroll
                for (int m = 1; m < 16; m <<= 1) {
                    s1 += __shfl_xor(s1, m);
                    s2 += __shfl_xor(s2, m);
                }
                if (lm16 == 0) {
                    const int o = row0 + mr * 16 + lg * 4 + r;
                    atomicAdd(&ostat[o], s1);
                    atomicAdd(&ostat[M + o], s2);
                }
            }
    }
}

// ---------------------------------------------------------------------------
// Depthwise 5x5 SAME + fused input BN+GELU.  in: f16 [B,CH,LL] (use coff),
// stats: [2*SZ] sum|sq.  out: f16 [B,128,LL].  grid (10,10,256).
// ---------------------------------------------------------------------------
__global__ __launch_bounds__(256) void dw5_kernel(
    const f16* __restrict__ in, const float* __restrict__ stat,
    int CH, int coff, int SZ,
    const float* __restrict__ wdw, f16* __restrict__ outp)
{
    __shared__ float tile[20][20];
    const int bc = blockIdx.z;
    const int b = bc >> 7, c = bc & 127;
    const float mean = stat[coff + c] * (1.f / NTOTF);
    const float var  = stat[SZ + coff + c] * (1.f / NTOTF) - mean * mean;
    const float rs   = rsqrtf(var + 1e-5f);

    const int h0 = blockIdx.y * 16, w0 = blockIdx.x * 16;
    const int tx = threadIdx.x & 15, ty = threadIdx.x >> 4;

    const f16* src = in + (size_t)(b * CH + coff + c) * LL;
    for (int idx = threadIdx.x; idx < 400; idx += 256) {
        const int r = idx / 20, col = idx - r * 20;
        const int gh = h0 + r - 2, gw = w0 + col - 2;
        float v = 0.f;
        if (gh >= 0 && gh < 160 && gw >= 0 && gw < 160)
            v = gelu_f(((float)src[gh * 160 + gw] - mean) * rs);
        tile[r][col] = v;
    }
    __syncthreads();

    const float* wp = wdw + c * 25;
    float wr[25];
#pragma unroll
    for (int q = 0; q < 25; ++q) wr[q] = wp[q];

    float acc = 0.f;
#pragma unroll
    for (int u = 0; u < 5; ++u)
#pragma unroll
        for (int v = 0; v < 5; ++v)
            acc = fmaf(wr[u * 5 + v], tile[ty + u][tx + v], acc);

    outp[(size_t)(b * 128 + c) * LL + (h0 + ty) * 160 + (w0 + tx)] = (f16)acc;
}

// ---------------------------------------------------------------------------
// Attention reduce via MFMA outer product.  For each (b,h):
//   kv[d,e] = (1/L) sum_p krelu[d,p] * vact[e,p]   (16x16)
//   ksum[d] = (1/L) sum_p krelu[d,p]
// grid 800 = (b:2, h:16, chunk:25 of 1024 pos), block 256 (4 waves).
// ---------------------------------------------------------------------------
__global__ __launch_bounds__(256) void att_reduce_kernel(
    const f16* __restrict__ KV, const f16* __restrict__ K2,
    const f16* __restrict__ V2, const float* __restrict__ stat,
    float* __restrict__ kvout, float* __restrict__ ksum)
{
    __shared__ float kvred[4][256];

    const int bx = blockIdx.x;
    const int b = bx / 400;
    const int rem = bx - b * 400;
    const int h = rem / 25;
    const int chunk = rem - h * 25;
    const int tid = threadIdx.x;
    const int wv = tid >> 6, l = tid & 63;
    const int ch = l & 15, kg = l >> 4;
    const bool half1 = h < 8;

    // per-lane BN constants (channel = ch)
    float mk = 0.f, rk = 1.f, mv = 0.f, rv = 1.f;
    if (half1) {
        const int ck = h * 16 + ch;
        mk = stat[ck] * (1.f / NTOTF);
        float va = stat[256 + ck] * (1.f / NTOTF) - mk * mk;
        rk = rsqrtf(va + 1e-5f);
        const int cv = 128 + h * 16 + ch;
        mv = stat[cv] * (1.f / NTOTF);
        va = stat[256 + cv] * (1.f / NTOTF) - mv * mv;
        rv = rsqrtf(va + 1e-5f);
    }

    const f16* kbase = half1 ? KV + (size_t)(b * 256 + h * 16 + ch) * LL
                             : K2 + (size_t)(b * 128 + (h - 8) * 16 + ch) * LL;
    const f16* vbase = half1 ? KV + (size_t)(b * 256 + 128 + h * 16 + ch) * LL
                             : V2 + (size_t)(b * 128 + (h - 8) * 16 + ch) * LL;

    f32x4 acc = (f32x4){0.f, 0.f, 0.f, 0.f};
    float ksacc = 0.f;
    const int base = chunk * 1024 + kg * 8;
#pragma unroll
    for (int it = 0; it < 8; ++it) {
        const int p = base + wv * 256 + it * 32;
        const f16x8 kf = *reinterpret_cast<const f16x8*>(kbase + p);
        const f16x8 vf = *reinterpret_cast<const f16x8*>(vbase + p);
        f16x8 ka, vb;
#pragma unroll
        for (int j = 0; j < 8; ++j) {
            float kl = (float)kf[j];
            if (half1) kl = gelu_f((kl - mk) * rk);
            kl = fmaxf(kl, 0.f);
            ksacc += kl;
            ka[j] = (f16)kl;
            float vl = (float)vf[j];
            if (half1) vl = gelu_f((vl - mv) * rv);
            vb[j] = (f16)vl;
        }
        acc = __builtin_amdgcn_mfma_f32_16x16x32_f16(ka, vb, acc, 0, 0, 0);
    }

    // block-reduce the four per-wave 16x16 tiles, then one atomic per entry
    constexpr float s = 1.f / (float)LL;
#pragma unroll
    for (int r = 0; r < 4; ++r)
        kvred[wv][(kg * 4 + r) * 16 + ch] = acc[r];
    __syncthreads();
    {
        float t = kvred[0][tid] + kvred[1][tid] + kvred[2][tid] + kvred[3][tid];
        atomicAdd(&kvout[(size_t)(b * 16 + h) * 256 + tid], t * s);
    }

    // ksum: lanes {l, l^16, l^32, l^48} share a channel
    float s1 = ksacc;
    s1 += __shfl_xor(s1, 16);
    s1 += __shfl_xor(s1, 32);
    if (l < 16) atomicAdd(&ksum[(size_t)(b * 16 + h) * 16 + ch], s1 * s);
}

// ---------------------------------------------------------------------------
// Attention apply.  grid 3200 = (b:2, h:16, chunk:100 of 256 pos), block 256
// (thread = one position).  q heads 0-7: BN+GELU+relu; heads 8-15: relu.
// ---------------------------------------------------------------------------
__global__ __launch_bounds__(256) void att_apply_kernel(
    const f16* __restrict__ Q, const f16* __restrict__ Q2,
    const float* __restrict__ statq,
    const float* __restrict__ kvin, const float* __restrict__ ksumin,
    f16* __restrict__ att)
{
    __shared__ float kvs[256];
    __shared__ float kss[16];
    __shared__ float mq[16], rq[16];

    const int bx = blockIdx.x;
    const int b = bx / 1600;
    const int rem = bx - b * 1600;
    const int h = rem / 100;
    const int chunk = rem - h * 100;
    const int tid = threadIdx.x;
    const int p = chunk * 256 + tid;

    kvs[tid] = kvin[(size_t)b * 4096 + h * 256 + tid];
    if (tid < 16) {
        kss[tid] = ksumin[(size_t)b * 256 + h * 16 + tid];
        if (h < 8) {
            const int c2 = h * 16 + tid;
            const float m  = statq[c2] * (1.f / NTOTF);
            const float va = statq[128 + c2] * (1.f / NTOTF) - m * m;
            mq[tid] = m; rq[tid] = rsqrtf(va + 1e-5f);
        } else { mq[tid] = 0.f; rq[tid] = 1.f; }
    }
    __syncthreads();

    const f16* qb = (h < 8) ? Q + (size_t)(b * 128 + h * 16) * LL
                            : Q2 + (size_t)(b * 128 + (h - 8) * 16) * LL;
    float s[16];
#pragma unroll
    for (int d = 0; d < 16; ++d) {
        float v = (float)qb[(size_t)d * LL + p];
        if (h < 8) v = gelu_f((v - mq[d]) * rq[d]);
        s[d] = fmaxf(v, 0.f);
    }
    float denom = 0.f;
#pragma unroll
    for (int d = 0; d < 16; ++d) denom = fmaf(s[d], kss[d], denom);
    const float z = 1.f / fmaxf(denom, 1e-6f);

    f16* ob = att + (size_t)(b * 256 + h * 16) * LL + p;
#pragma unroll
    for (int e = 0; e < 16; ++e) {
        float acc = 0.f;
#pragma unroll
        for (int d = 0; d < 16; ++d)
            acc = fmaf(s[d], kvs[d * 16 + e], acc);
        ob[(size_t)e * LL] = (f16)(acc * z);
    }
}

// ---------------------------------------------------------------------------
// Fused tail: t[c] = resid + gelu(bn(yconv)); out = LN_c(t)*w+b.
// grid 800 (64 positions/block), block 256.
// ---------------------------------------------------------------------------
template <bool RES32, bool OUT32>
__global__ __launch_bounds__(256) void fuse_ln_kernel(
    const f16* __restrict__ yconv, const void* __restrict__ residv,
    const float* __restrict__ stat,
    const float* __restrict__ lnw, const float* __restrict__ lnb,
    void* __restrict__ outv)
{
    __shared__ float t[128][64];
    __shared__ float mrs[128][2];
    __shared__ float red[4][64][2];
    __shared__ float mln[64], rln[64];

    const int bx = blockIdx.x;
    const int b = bx / 400, p0 = (bx - b * 400) * 64;
    const int tid = threadIdx.x;

    if (tid < 128) {
        const float mean = stat[tid] * (1.f / NTOTF);
        const float var  = stat[128 + tid] * (1.f / NTOTF) - mean * mean;
        mrs[tid][0] = mean; mrs[tid][1] = rsqrtf(var + 1e-5f);
    }
    __syncthreads();

    for (int idx = tid; idx < 8192; idx += 256) {
        const int c = idx >> 6, i = idx & 63;
        const size_t off = (size_t)(b * 128 + c) * LL + p0 + i;
        const float g = gelu_f(((float)yconv[off] - mrs[c][0]) * mrs[c][1]);
        const float r = RES32 ? reinterpret_cast<const float*>(residv)[off]
                              : (float)reinterpret_cast<const f16*>(residv)[off];
        t[c][i] = g + r;
    }
    __syncthreads();

    {
        const int i = tid & 63, q = tid >> 6;
        float ps = 0.f, pq = 0.f;
        for (int c = q * 32; c < q * 32 + 32; ++c) {
            const float v = t[c][i];
            ps += v; pq += v * v;
        }
        red[q][i][0] = ps; red[q][i][1] = pq;
    }
    __syncthreads();
    if (tid < 64) {
        float s1 = 0.f, s2 = 0.f;
#pragma unroll
        for (int q = 0; q < 4; ++q) { s1 += red[q][tid][0]; s2 += red[q][tid][1]; }
        const float m = s1 * (1.f / 128.f);
        const float var = s2 * (1.f / 128.f) - m * m;
        mln[tid] = m; rln[tid] = rsqrtf(var + 1e-5f);
    }
    __syncthreads();

    for (int idx = tid; idx < 8192; idx += 256) {
        const int c = idx >> 6, i = idx & 63;
        const float v = (t[c][i] - mln[i]) * rln[i] * lnw[c] + lnb[c];
        const size_t off = (size_t)(b * 128 + c) * LL + p0 + i;
        if (OUT32) reinterpret_cast<float*>(outv)[off] = v;
        else reinterpret_cast<f16*>(outv)[off] = (f16)v;
    }
}

// ---------------------------------------------------------------------------
// wcomb[o, c2] = sum_m wmerge[o, m] * wproj[m, c2]   (128 x 256, fp32)
// ---------------------------------------------------------------------------
__global__ __launch_bounds__(256) void wcomb_kernel(
    const float* __restrict__ wmerge, const float* __restrict__ wproj,
    float* __restrict__ wc)
{
    const int o = blockIdx.x;
    const int c2 = threadIdx.x;
    float acc = 0.f;
#pragma unroll 4
    for (int m = 0; m < 128; ++m)
        acc = fmaf(wmerge[o * 128 + m], wproj[m * 256 + c2], acc);
    wc[o * 256 + c2] = acc;
}

// ---------------------------------------------------------------------------
extern "C" void kernel_launch(void* const* d_in, const int* in_sizes, int n_in,
                              void* d_out, int out_size, void* d_ws, size_t ws_size,
                              hipStream_t stream)
{
    const float* x      = (const float*)d_in[0];
    const float* source = (const float*)d_in[1];
    const float* wq = (const float*)d_in[2];  const float* bq = (const float*)d_in[3];
    const float* wk = (const float*)d_in[4];  const float* bk = (const float*)d_in[5];
    const float* wvw = (const float*)d_in[6]; const float* bvb = (const float*)d_in[7];
    const float* dwq = (const float*)d_in[8];  const float* pwq = (const float*)d_in[9];
    const float* dwk = (const float*)d_in[10]; const float* pwk = (const float*)d_in[11];
    const float* dwv = (const float*)d_in[12]; const float* pwv = (const float*)d_in[13];
    const float* wproj  = (const float*)d_in[14];
    const float* wmerge = (const float*)d_in[15]; const float* bmerge = (const float*)d_in[16];
    const float* wff1 = (const float*)d_in[17]; const float* bff1 = (const float*)d_in[18];
    const float* wff2 = (const float*)d_in[19]; const float* bff2 = (const float*)d_in[20];
    const float* ln1w = (const float*)d_in[21]; const float* ln1b = (const float*)d_in[22];
    const float* ln2w = (const float*)d_in[23]; const float* ln2b = (const float*)d_in[24];

    const size_t UNITB = (size_t)2 * 128 * LL * sizeof(f16);  // 13,107,200 B
    char* w = (char*)d_ws;
    f16* qraw  = (f16*)w; w += UNITB;
    f16* kvraw = (f16*)w; w += 2 * UNITB;   // k: rows 0-127, v: 128-255
    f16* dwtmp = (f16*)w; w += UNITB;
    f16* q2raw = (f16*)w; w += UNITB;
    f16* k2raw = (f16*)w; w += UNITB;
    f16* v2raw = (f16*)w; w += UNITB;
    f16* att   = (f16*)w; w += 2 * UNITB;
    f16* y2raw = (f16*)w; w += UNITB;
    f16* msg   = (f16*)w; w += UNITB;
    f16* ff1raw= (f16*)w; w += 2 * UNITB;
    f16* ff2raw= (f16*)w; w += UNITB;

    float* zbase = (float*)w;
    float* kvred = zbase;              // 8192
    float* ksum  = zbase + 8192;       // 512
    float* sQ    = zbase + 8704;       // 256 (sum128|sq128)
    float* sKV   = sQ + 256;           // 512 (sum256|sq256)
    float* sM    = sKV + 512;          // 256
    float* sF1   = sM + 256;           // 512
    float* sF2   = sF1 + 512;          // 256
    const size_t zcount = 8192 + 512 + 256 + 512 + 256 + 512 + 256;  // 10496
    float* wcomb = zbase + zcount;     // 128*256 fp32

    hipMemsetAsync(zbase, 0, zcount * sizeof(float), stream);
    wcomb_kernel<<<128, 256, 0, stream>>>(wmerge, wproj, wcomb);

    // q / (k,v) 1x1 convs with BN stats          <M,K,LOOP,IN32,LDG,TWOW,BIAS,STATS>
    gemm_kernel<128,128,false,true,false,false,true,true><<<800, 256, 0, stream>>>(
        x, wq, nullptr, bq, nullptr, nullptr, qraw, sQ, 800);
    gemm_kernel<256,128,false,true,false,true,true,true><<<800, 256, 0, stream>>>(
        source, wk, wvw, bk, bvb, nullptr, kvraw, sKV, 800);

    // multiscale branch: BN+GELU fused into dw5, then pointwise GEMM
    dim3 dwg(10, 10, 256);
    dw5_kernel<<<dwg, 256, 0, stream>>>(qraw, sQ, 128, 0, 128, dwq, dwtmp);
    gemm_kernel<128,128,false,false,false,false,false,false><<<800, 256, 0, stream>>>(
        dwtmp, pwq, nullptr, nullptr, nullptr, nullptr, q2raw, nullptr, 800);
    dw5_kernel<<<dwg, 256, 0, stream>>>(kvraw, sKV, 256, 0, 256, dwk, dwtmp);
    gemm_kernel<128,128,false,false,false,false,false,false><<<800, 256, 0, stream>>>(
        dwtmp, pwk, nullptr, nullptr, nullptr, nullptr, k2raw, nullptr, 800);
    dw5_kernel<<<dwg, 256, 0, stream>>>(kvraw, sKV, 256, 128, 256, dwv, dwtmp);
    gemm_kernel<128,128,false,false,false,false,false,false><<<800, 256, 0, stream>>>(
        dwtmp, pwv, nullptr, nullptr, nullptr, nullptr, v2raw, nullptr, 800);

    // linear attention
    att_reduce_kernel<<<800, 256, 0, stream>>>(kvraw, k2raw, v2raw, sKV, kvred, ksum);
    att_apply_kernel<<<3200, 256, 0, stream>>>(qraw, q2raw, sQ, kvred, ksum, att);

    // merged (wmerge @ wproj) conv with BN stats
    gemm_kernel<128,256,true,false,false,false,true,true><<<400, 256, 0, stream>>>(
        att, wcomb, nullptr, bmerge, nullptr, nullptr, y2raw, sM, 800);

    // msg = LN1(x + gelu(bn(y2)))
    fuse_ln_kernel<true,false><<<800, 256, 0, stream>>>(
        y2raw, x, sM, ln1w, ln1b, msg);

    // FFN: ff1 GEMM; ff2 GEMM with BN+GELU fused on load
    gemm_kernel<256,128,false,false,false,false,true,true><<<800, 256, 0, stream>>>(
        msg, wff1, nullptr, bff1, nullptr, nullptr, ff1raw, sF1, 800);
    gemm_kernel<128,256,true,false,true,false,true,true><<<400, 256, 0, stream>>>(
        ff1raw, wff2, nullptr, bff2, nullptr, sF1, ff2raw, sF2, 800);

    // out = LN2(msg + gelu(bn(ff2)))
    fuse_ln_kernel<false,true><<<800, 256, 0, stream>>>(
        ff2raw, msg, sF2, ln2w, ln2b, (float*)d_out);
}

// Round 6
// 406.511 us; speedup vs baseline: 1.6384x; 1.6384x over previous
//
#include <hip/hip_runtime.h>
#include <math.h>

#define LL 25600          // H*W
#define NTOTF 51200.f     // B*L (batch-norm N)

using f16   = _Float16;
using f16x8 = __attribute__((ext_vector_type(8))) _Float16;
using f16x4 = __attribute__((ext_vector_type(4))) _Float16;
using f32x4 = __attribute__((ext_vector_type(4))) float;

__device__ __forceinline__ float gelu_f(float v) {
    return 0.5f * v * (1.f + erff(v * 0.70710678118654752440f));
}

// ---------------------------------------------------------------------------
// f16 MFMA GEMM:  Y[b, o, p] = bias[o] + sum_c W[o,c] * X[b, c, p]
//   X: [B, K, LL] (fp32 if IN32 else f16); W: fp32 [M,K] row-major
//   (TWOW: rows 0-127 from WA, 128-255 from WB); Y: f16 [B, M, LL].
//   LDG: apply BN(lstat)+GELU to X elements while staging to LDS.
//   STATS: accumulate per-o sum/sumsq of Y (pre-f16-rounding) into ostat[2M].
// W in REGISTERS as the MFMA *B*-operand (col=channel); X chunk staged in LDS
// (XOR-swizzled, double-buffered) read as the *A*-operand (row=position).
// D layout then gives each lane 4 CONSECUTIVE positions -> f16x4 stores.
// Block: 256 thr (4 waves); wave owns M/4 output channels; chunk: 64 pos.
// Grid loops over chunks (grid=400, nchunk=800 -> 2 chunks/block).
// ---------------------------------------------------------------------------
template <int M, int K, bool IN32, bool LDG, bool TWOW, bool BIAS, bool STATS>
__global__ __launch_bounds__(256) void gemm_kernel(
    const void* __restrict__ Xin,
    const float* __restrict__ WA, const float* __restrict__ WB,
    const float* __restrict__ biasA, const float* __restrict__ biasB,
    const float* __restrict__ lstat,     // [2K] sum|sq for load-side BN
    f16* __restrict__ Y,
    float* __restrict__ ostat,           // [2M] sum|sq
    int nchunk)
{
    constexpr int MR  = M / 64;    // 16-channel frags per wave
    constexpr int KS  = K / 32;    // k-steps
    constexpr int CPT = K / 4;     // channels staged per thread
    constexpr int CPV = CPT / 8;
    static_assert(CPT % 8 == 0, "");

    __shared__ f16 Xs[2][64 * K];
    __shared__ float lmrs[LDG ? 2 * K : 2];

    const int tid  = threadIdx.x;
    const int lane = tid & 63;
    const int wv   = tid >> 6;
    const int lm16 = lane & 15, lg = lane >> 4;
    const int row0 = wv * (M / 4);
    const int i    = lane;          // position within chunk
    const int g0   = wv * CPT;      // first channel staged by this thread

    // ---- W -> registers (B-operand frags), fp32 -> f16 ----
    f16x8 wfr[KS][MR];
#pragma unroll
    for (int k = 0; k < KS; ++k) {
        const int col = k * 32 + lg * 8;
#pragma unroll
        for (int mr = 0; mr < MR; ++mr) {
            const int row = row0 + mr * 16 + lm16;
            const float* wp = (TWOW && row >= 128)
                                  ? WB + (size_t)(row - 128) * K + col
                                  : WA + (size_t)row * K + col;
            const float4 wa = *reinterpret_cast<const float4*>(wp);
            const float4 wb2 = *reinterpret_cast<const float4*>(wp + 4);
            f16x8 v;
            v[0] = (f16)wa.x; v[1] = (f16)wa.y; v[2] = (f16)wa.z; v[3] = (f16)wa.w;
            v[4] = (f16)wb2.x; v[5] = (f16)wb2.y; v[6] = (f16)wb2.z; v[7] = (f16)wb2.w;
            wfr[k][mr] = v;
        }
    }
    if (LDG) {
        for (int c = tid; c < K; c += 256) {
            const float m  = lstat[c] * (1.f / NTOTF);
            const float va = lstat[K + c] * (1.f / NTOTF) - m * m;
            lmrs[c] = m; lmrs[K + c] = rsqrtf(va + 1e-5f);
        }
    }

    // ---- bias (per-mr scalar) + stats regs ----
    float bvv[MR];
    float st1[MR], st2[MR];
#pragma unroll
    for (int mr = 0; mr < MR; ++mr) {
        const int o = row0 + mr * 16 + lm16;
        bvv[mr] = BIAS ? ((TWOW && o >= 128) ? biasB[o - 128] : biasA[o]) : 0.f;
        st1[mr] = 0.f; st2[mr] = 0.f;
    }

    f16x8 xrp[CPV];
    auto load_regs = [&](int t) {
        const int bb = t / 400, pp0 = (t - bb * 400) * 64;
#pragma unroll
        for (int v = 0; v < CPV; ++v)
#pragma unroll
            for (int jj = 0; jj < 8; ++jj) {
                const size_t off = (size_t)(bb * K + g0 + v * 8 + jj) * LL + pp0 + i;
                xrp[v][jj] = IN32 ? (f16)reinterpret_cast<const float*>(Xin)[off]
                                  : reinterpret_cast<const f16*>(Xin)[off];
            }
    };
    auto store_lds = [&](int buf) {
#pragma unroll
        for (int v = 0; v < CPV; ++v) {
            f16x8 v8 = xrp[v];
            if (LDG) {
#pragma unroll
                for (int jj = 0; jj < 8; ++jj) {
                    const int c = g0 + v * 8 + jj;
                    v8[jj] = (f16)gelu_f(((float)v8[jj] - lmrs[c]) * lmrs[K + c]);
                }
            }
            const int c0 = g0 + v * 8;
            *reinterpret_cast<f16x8*>(
                &Xs[buf][(size_t)i * K + (c0 ^ ((i & 7) << 3))]) = v8;
        }
    };

    __syncthreads();                       // lmrs visible
    int t = blockIdx.x;
    int cur = 0;
    load_regs(t);
    store_lds(0);
    __syncthreads();

    while (true) {
        const int tn = t + gridDim.x;
        const bool nxt = tn < nchunk;
        if (nxt) load_regs(tn);            // next-chunk global loads in flight

        const int bb = t / 400, pp0 = (t - bb * 400) * 64;
        f32x4 acc[MR][4];
#pragma unroll
        for (int mr = 0; mr < MR; ++mr)
#pragma unroll
            for (int nr = 0; nr < 4; ++nr)
                acc[mr][nr] = (f32x4){0.f, 0.f, 0.f, 0.f};

#pragma unroll
        for (int k = 0; k < KS; ++k) {
            const int kc = k * 32 + lg * 8;
            f16x8 xa[4];
#pragma unroll
            for (int nr = 0; nr < 4; ++nr) {
                const int pos = nr * 16 + lm16;
                xa[nr] = *reinterpret_cast<const f16x8*>(
                    &Xs[cur][(size_t)pos * K + (kc ^ ((pos & 7) << 3))]);
            }
#pragma unroll
            for (int mr = 0; mr < MR; ++mr)
#pragma unroll
                for (int nr = 0; nr < 4; ++nr)
                    acc[mr][nr] = __builtin_amdgcn_mfma_f32_16x16x32_f16(
                        xa[nr], wfr[k][mr], acc[mr][nr], 0, 0, 0);
        }

        // epilogue: bias, f16x4 vector store (4 consecutive positions), stats
#pragma unroll
        for (int mr = 0; mr < MR; ++mr) {
            const int o = row0 + mr * 16 + lm16;
            f16* yb = Y + (size_t)(bb * M + o) * LL + pp0;
#pragma unroll
            for (int nr = 0; nr < 4; ++nr) {
                f16x4 o4;
#pragma unroll
                for (int r = 0; r < 4; ++r) {
                    const float v = acc[mr][nr][r] + bvv[mr];
                    o4[r] = (f16)v;
                    if (STATS) { st1[mr] += v; st2[mr] += v * v; }
                }
                *reinterpret_cast<f16x4*>(yb + nr * 16 + lg * 4) = o4;
            }
        }

        if (!nxt) break;
        store_lds(cur ^ 1);
        __syncthreads();
        cur ^= 1; t = tn;
    }

    if (STATS) {
#pragma unroll
        for (int mr = 0; mr < MR; ++mr) {
            float s1 = st1[mr], s2 = st2[mr];
            s1 += __shfl_xor(s1, 16); s2 += __shfl_xor(s2, 16);
            s1 += __shfl_xor(s1, 32); s2 += __shfl_xor(s2, 32);
            if (lane < 16) {
                const int o = row0 + mr * 16 + lm16;
                atomicAdd(&ostat[o], s1);
                atomicAdd(&ostat[M + o], s2);
            }
        }
    }
}

// ---------------------------------------------------------------------------
// Depthwise 5x5 SAME + fused input BN+GELU.  in: f16 [B,CH,LL] (use coff),
// stats: [2*SZ] sum|sq.  out: f16 [B,128,LL].  grid (10,10,256).
// ---------------------------------------------------------------------------
__global__ __launch_bounds__(256) void dw5_kernel(
    const f16* __restrict__ in, const float* __restrict__ stat,
    int CH, int coff, int SZ,
    const float* __restrict__ wdw, f16* __restrict__ outp)
{
    __shared__ float tile[20][20];
    const int bc = blockIdx.z;
    const int b = bc >> 7, c = bc & 127;
    const float mean = stat[coff + c] * (1.f / NTOTF);
    const float var  = stat[SZ + coff + c] * (1.f / NTOTF) - mean * mean;
    const float rs   = rsqrtf(var + 1e-5f);

    const int h0 = blockIdx.y * 16, w0 = blockIdx.x * 16;
    const int tx = threadIdx.x & 15, ty = threadIdx.x >> 4;

    const f16* src = in + (size_t)(b * CH + coff + c) * LL;
    for (int idx = threadIdx.x; idx < 400; idx += 256) {
        const int r = idx / 20, col = idx - r * 20;
        const int gh = h0 + r - 2, gw = w0 + col - 2;
        float v = 0.f;
        if (gh >= 0 && gh < 160 && gw >= 0 && gw < 160)
            v = gelu_f(((float)src[gh * 160 + gw] - mean) * rs);
        tile[r][col] = v;
    }
    __syncthreads();

    const float* wp = wdw + c * 25;
    float wr[25];
#pragma unroll
    for (int q = 0; q < 25; ++q) wr[q] = wp[q];

    float acc = 0.f;
#pragma unroll
    for (int u = 0; u < 5; ++u)
#pragma unroll
        for (int v = 0; v < 5; ++v)
            acc = fmaf(wr[u * 5 + v], tile[ty + u][tx + v], acc);

    outp[(size_t)(b * 128 + c) * LL + (h0 + ty) * 160 + (w0 + tx)] = (f16)acc;
}

// ---------------------------------------------------------------------------
// Attention reduce via MFMA outer product.  For each (b,h):
//   kv[d,e] = (1/L) sum_p krelu[d,p] * vact[e,p]   (16x16)
//   ksum[d] = (1/L) sum_p krelu[d,p]
// grid 800 = (b:2, h:16, chunk:25 of 1024 pos), block 256 (4 waves).
// ---------------------------------------------------------------------------
__global__ __launch_bounds__(256) void att_reduce_kernel(
    const f16* __restrict__ KV, const f16* __restrict__ K2,
    const f16* __restrict__ V2, const float* __restrict__ stat,
    float* __restrict__ kvout, float* __restrict__ ksum)
{
    __shared__ float kvred[4][256];

    const int bx = blockIdx.x;
    const int b = bx / 400;
    const int rem = bx - b * 400;
    const int h = rem / 25;
    const int chunk = rem - h * 25;
    const int tid = threadIdx.x;
    const int wv = tid >> 6, l = tid & 63;
    const int ch = l & 15, kg = l >> 4;
    const bool half1 = h < 8;

    // per-lane BN constants (channel = ch)
    float mk = 0.f, rk = 1.f, mv = 0.f, rv = 1.f;
    if (half1) {
        const int ck = h * 16 + ch;
        mk = stat[ck] * (1.f / NTOTF);
        float va = stat[256 + ck] * (1.f / NTOTF) - mk * mk;
        rk = rsqrtf(va + 1e-5f);
        const int cv = 128 + h * 16 + ch;
        mv = stat[cv] * (1.f / NTOTF);
        va = stat[256 + cv] * (1.f / NTOTF) - mv * mv;
        rv = rsqrtf(va + 1e-5f);
    }

    const f16* kbase = half1 ? KV + (size_t)(b * 256 + h * 16 + ch) * LL
                             : K2 + (size_t)(b * 128 + (h - 8) * 16 + ch) * LL;
    const f16* vbase = half1 ? KV + (size_t)(b * 256 + 128 + h * 16 + ch) * LL
                             : V2 + (size_t)(b * 128 + (h - 8) * 16 + ch) * LL;

    f32x4 acc = (f32x4){0.f, 0.f, 0.f, 0.f};
    float ksacc = 0.f;
    const int base = chunk * 1024 + kg * 8;
#pragma unroll
    for (int it = 0; it < 8; ++it) {
        const int p = base + wv * 256 + it * 32;
        const f16x8 kf = *reinterpret_cast<const f16x8*>(kbase + p);
        const f16x8 vf = *reinterpret_cast<const f16x8*>(vbase + p);
        f16x8 ka, vb;
#pragma unroll
        for (int j = 0; j < 8; ++j) {
            float kl = (float)kf[j];
            if (half1) kl = gelu_f((kl - mk) * rk);
            kl = fmaxf(kl, 0.f);
            ksacc += kl;
            ka[j] = (f16)kl;
            float vl = (float)vf[j];
            if (half1) vl = gelu_f((vl - mv) * rv);
            vb[j] = (f16)vl;
        }
        acc = __builtin_amdgcn_mfma_f32_16x16x32_f16(ka, vb, acc, 0, 0, 0);
    }

    // block-reduce the four per-wave 16x16 tiles, then one atomic per entry
    constexpr float s = 1.f / (float)LL;
#pragma unroll
    for (int r = 0; r < 4; ++r)
        kvred[wv][(kg * 4 + r) * 16 + ch] = acc[r];
    __syncthreads();
    {
        float t = kvred[0][tid] + kvred[1][tid] + kvred[2][tid] + kvred[3][tid];
        atomicAdd(&kvout[(size_t)(b * 16 + h) * 256 + tid], t * s);
    }

    // ksum: lanes {l, l^16, l^32, l^48} share a channel
    float s1 = ksacc;
    s1 += __shfl_xor(s1, 16);
    s1 += __shfl_xor(s1, 32);
    if (l < 16) atomicAdd(&ksum[(size_t)(b * 16 + h) * 16 + ch], s1 * s);
}

// ---------------------------------------------------------------------------
// Attention apply.  grid 3200 = (b:2, h:16, chunk:100 of 256 pos), block 256
// (thread = one position).  q heads 0-7: BN+GELU+relu; heads 8-15: relu.
// ---------------------------------------------------------------------------
__global__ __launch_bounds__(256) void att_apply_kernel(
    const f16* __restrict__ Q, const f16* __restrict__ Q2,
    const float* __restrict__ statq,
    const float* __restrict__ kvin, const float* __restrict__ ksumin,
    f16* __restrict__ att)
{
    __shared__ float kvs[256];
    __shared__ float kss[16];
    __shared__ float mq[16], rq[16];

    const int bx = blockIdx.x;
    const int b = bx / 1600;
    const int rem = bx - b * 1600;
    const int h = rem / 100;
    const int chunk = rem - h * 100;
    const int tid = threadIdx.x;
    const int p = chunk * 256 + tid;

    kvs[tid] = kvin[(size_t)b * 4096 + h * 256 + tid];
    if (tid < 16) {
        kss[tid] = ksumin[(size_t)b * 256 + h * 16 + tid];
        if (h < 8) {
            const int c2 = h * 16 + tid;
            const float m  = statq[c2] * (1.f / NTOTF);
            const float va = statq[128 + c2] * (1.f / NTOTF) - m * m;
            mq[tid] = m; rq[tid] = rsqrtf(va + 1e-5f);
        } else { mq[tid] = 0.f; rq[tid] = 1.f; }
    }
    __syncthreads();

    const f16* qb = (h < 8) ? Q + (size_t)(b * 128 + h * 16) * LL
                            : Q2 + (size_t)(b * 128 + (h - 8) * 16) * LL;
    float s[16];
#pragma unroll
    for (int d = 0; d < 16; ++d) {
        float v = (float)qb[(size_t)d * LL + p];
        if (h < 8) v = gelu_f((v - mq[d]) * rq[d]);
        s[d] = fmaxf(v, 0.f);
    }
    float denom = 0.f;
#pragma unroll
    for (int d = 0; d < 16; ++d) denom = fmaf(s[d], kss[d], denom);
    const float z = 1.f / fmaxf(denom, 1e-6f);

    f16* ob = att + (size_t)(b * 256 + h * 16) * LL + p;
#pragma unroll
    for (int e = 0; e < 16; ++e) {
        float acc = 0.f;
#pragma unroll
        for (int d = 0; d < 16; ++d)
            acc = fmaf(s[d], kvs[d * 16 + e], acc);
        ob[(size_t)e * LL] = (f16)(acc * z);
    }
}

// ---------------------------------------------------------------------------
// Fused tail: t[c] = resid + gelu(bn(yconv)); out = LN_c(t)*w+b.
// grid 800 (64 positions/block), block 256.
// ---------------------------------------------------------------------------
template <bool RES32, bool OUT32>
__global__ __launch_bounds__(256) void fuse_ln_kernel(
    const f16* __restrict__ yconv, const void* __restrict__ residv,
    const float* __restrict__ stat,
    const float* __restrict__ lnw, const float* __restrict__ lnb,
    void* __restrict__ outv)
{
    __shared__ float t[128][64];
    __shared__ float mrs[128][2];
    __shared__ float red[4][64][2];
    __shared__ float mln[64], rln[64];

    const int bx = blockIdx.x;
    const int b = bx / 400, p0 = (bx - b * 400) * 64;
    const int tid = threadIdx.x;

    if (tid < 128) {
        const float mean = stat[tid] * (1.f / NTOTF);
        const float var  = stat[128 + tid] * (1.f / NTOTF) - mean * mean;
        mrs[tid][0] = mean; mrs[tid][1] = rsqrtf(var + 1e-5f);
    }
    __syncthreads();

    for (int idx = tid; idx < 8192; idx += 256) {
        const int c = idx >> 6, i = idx & 63;
        const size_t off = (size_t)(b * 128 + c) * LL + p0 + i;
        const float g = gelu_f(((float)yconv[off] - mrs[c][0]) * mrs[c][1]);
        const float r = RES32 ? reinterpret_cast<const float*>(residv)[off]
                              : (float)reinterpret_cast<const f16*>(residv)[off];
        t[c][i] = g + r;
    }
    __syncthreads();

    {
        const int i = tid & 63, q = tid >> 6;
        float ps = 0.f, pq = 0.f;
        for (int c = q * 32; c < q * 32 + 32; ++c) {
            const float v = t[c][i];
            ps += v; pq += v * v;
        }
        red[q][i][0] = ps; red[q][i][1] = pq;
    }
    __syncthreads();
    if (tid < 64) {
        float s1 = 0.f, s2 = 0.f;
#pragma unroll
        for (int q = 0; q < 4; ++q) { s1 += red[q][tid][0]; s2 += red[q][tid][1]; }
        const float m = s1 * (1.f / 128.f);
        const float var = s2 * (1.f / 128.f) - m * m;
        mln[tid] = m; rln[tid] = rsqrtf(var + 1e-5f);
    }
    __syncthreads();

    for (int idx = tid; idx < 8192; idx += 256) {
        const int c = idx >> 6, i = idx & 63;
        const float v = (t[c][i] - mln[i]) * rln[i] * lnw[c] + lnb[c];
        const size_t off = (size_t)(b * 128 + c) * LL + p0 + i;
        if (OUT32) reinterpret_cast<float*>(outv)[off] = v;
        else reinterpret_cast<f16*>(outv)[off] = (f16)v;
    }
}

// ---------------------------------------------------------------------------
// wcomb[o, c2] = sum_m wmerge[o, m] * wproj[m, c2]   (128 x 256, fp32)
// ---------------------------------------------------------------------------
__global__ __launch_bounds__(256) void wcomb_kernel(
    const float* __restrict__ wmerge, const float* __restrict__ wproj,
    float* __restrict__ wc)
{
    const int o = blockIdx.x;
    const int c2 = threadIdx.x;
    float acc = 0.f;
#pragma unroll 4
    for (int m = 0; m < 128; ++m)
        acc = fmaf(wmerge[o * 128 + m], wproj[m * 256 + c2], acc);
    wc[o * 256 + c2] = acc;
}

// ---------------------------------------------------------------------------
extern "C" void kernel_launch(void* const* d_in, const int* in_sizes, int n_in,
                              void* d_out, int out_size, void* d_ws, size_t ws_size,
                              hipStream_t stream)
{
    const float* x      = (const float*)d_in[0];
    const float* source = (const float*)d_in[1];
    const float* wq = (const float*)d_in[2];  const float* bq = (const float*)d_in[3];
    const float* wk = (const float*)d_in[4];  const float* bk = (const float*)d_in[5];
    const float* wvw = (const float*)d_in[6]; const float* bvb = (const float*)d_in[7];
    const float* dwq = (const float*)d_in[8];  const float* pwq = (const float*)d_in[9];
    const float* dwk = (const float*)d_in[10]; const float* pwk = (const float*)d_in[11];
    const float* dwv = (const float*)d_in[12]; const float* pwv = (const float*)d_in[13];
    const float* wproj  = (const float*)d_in[14];
    const float* wmerge = (const float*)d_in[15]; const float* bmerge = (const float*)d_in[16];
    const float* wff1 = (const float*)d_in[17]; const float* bff1 = (const float*)d_in[18];
    const float* wff2 = (const float*)d_in[19]; const float* bff2 = (const float*)d_in[20];
    const float* ln1w = (const float*)d_in[21]; const float* ln1b = (const float*)d_in[22];
    const float* ln2w = (const float*)d_in[23]; const float* ln2b = (const float*)d_in[24];

    const size_t UNITB = (size_t)2 * 128 * LL * sizeof(f16);  // 13,107,200 B
    char* w = (char*)d_ws;
    f16* qraw  = (f16*)w; w += UNITB;
    f16* kvraw = (f16*)w; w += 2 * UNITB;   // k: rows 0-127, v: 128-255
    f16* dwtmp = (f16*)w; w += UNITB;
    f16* q2raw = (f16*)w; w += UNITB;
    f16* k2raw = (f16*)w; w += UNITB;
    f16* v2raw = (f16*)w; w += UNITB;
    f16* att   = (f16*)w; w += 2 * UNITB;
    f16* y2raw = (f16*)w; w += UNITB;
    f16* msg   = (f16*)w; w += UNITB;
    f16* ff1raw= (f16*)w; w += 2 * UNITB;
    f16* ff2raw= (f16*)w; w += UNITB;

    float* zbase = (float*)w;
    float* kvred = zbase;              // 8192
    float* ksum  = zbase + 8192;       // 512
    float* sQ    = zbase + 8704;       // 256 (sum128|sq128)
    float* sKV   = sQ + 256;           // 512 (sum256|sq256)
    float* sM    = sKV + 512;          // 256
    float* sF1   = sM + 256;           // 512
    float* sF2   = sF1 + 512;          // 256
    const size_t zcount = 8192 + 512 + 256 + 512 + 256 + 512 + 256;  // 10496
    float* wcomb = zbase + zcount;     // 128*256 fp32

    hipMemsetAsync(zbase, 0, zcount * sizeof(float), stream);
    wcomb_kernel<<<128, 256, 0, stream>>>(wmerge, wproj, wcomb);

    // q / (k,v) 1x1 convs with BN stats          <M,K,IN32,LDG,TWOW,BIAS,STATS>
    gemm_kernel<128,128,true,false,false,true,true><<<400, 256, 0, stream>>>(
        x, wq, nullptr, bq, nullptr, nullptr, qraw, sQ, 800);
    gemm_kernel<256,128,true,false,true,true,true><<<400, 256, 0, stream>>>(
        source, wk, wvw, bk, bvb, nullptr, kvraw, sKV, 800);

    // multiscale branch: BN+GELU fused into dw5, then pointwise GEMM
    dim3 dwg(10, 10, 256);
    dw5_kernel<<<dwg, 256, 0, stream>>>(qraw, sQ, 128, 0, 128, dwq, dwtmp);
    gemm_kernel<128,128,false,false,false,false,false><<<400, 256, 0, stream>>>(
        dwtmp, pwq, nullptr, nullptr, nullptr, nullptr, q2raw, nullptr, 800);
    dw5_kernel<<<dwg, 256, 0, stream>>>(kvraw, sKV, 256, 0, 256, dwk, dwtmp);
    gemm_kernel<128,128,false,false,false,false,false><<<400, 256, 0, stream>>>(
        dwtmp, pwk, nullptr, nullptr, nullptr, nullptr, k2raw, nullptr, 800);
    dw5_kernel<<<dwg, 256, 0, stream>>>(kvraw, sKV, 256, 128, 256, dwv, dwtmp);
    gemm_kernel<128,128,false,false,false,false,false><<<400, 256, 0, stream>>>(
        dwtmp, pwv, nullptr, nullptr, nullptr, nullptr, v2raw, nullptr, 800);

    // linear attention
    att_reduce_kernel<<<800, 256, 0, stream>>>(kvraw, k2raw, v2raw, sKV, kvred, ksum);
    att_apply_kernel<<<3200, 256, 0, stream>>>(qraw, q2raw, sQ, kvred, ksum, att);

    // merged (wmerge @ wproj) conv with BN stats
    gemm_kernel<128,256,false,false,false,true,true><<<400, 256, 0, stream>>>(
        att, wcomb, nullptr, bmerge, nullptr, nullptr, y2raw, sM, 800);

    // msg = LN1(x + gelu(bn(y2)))
    fuse_ln_kernel<true,false><<<800, 256, 0, stream>>>(
        y2raw, x, sM, ln1w, ln1b, msg);

    // FFN: ff1 GEMM; ff2 GEMM with BN+GELU fused on load
    gemm_kernel<256,128,false,false,false,true,true><<<400, 256, 0, stream>>>(
        msg, wff1, nullptr, bff1, nullptr, nullptr, ff1raw, sF1, 800);
    gemm_kernel<128,256,false,true,false,true,true><<<400, 256, 0, stream>>>(
        ff1raw, wff2, nullptr, bff2, nullptr, sF1, ff2raw, sF2, 800);

    // out = LN2(msg + gelu(bn(ff2)))
    fuse_ln_kernel<false,true><<<800, 256, 0, stream>>>(
        ff2raw, msg, sF2, ln2w, ln2b, (float*)d_out);
}